// Round 1
// baseline (89.037 us; speedup 1.0000x reference)
//
#include <hip/hip_runtime.h>

// Per-row vector quantization:
//   x: [4096, 2048] fp32, values: [4096, 16] fp32
//   out[r][c] = values[r][argmin_v (x[r][c] - values[r][v])^2]
// Bit-exact replication of the numpy reference: fp32 sub, fp32 square,
// strict '<' so the FIRST minimal index wins ties (argmin semantics).

#define N_ROWS 4096
#define N_COLS 2048
#define N_VALS 16

__global__ __launch_bounds__(256) void vq_rowcodebook_kernel(
    const float* __restrict__ x,
    const float* __restrict__ values,
    float* __restrict__ out)
{
    const int row = blockIdx.x;

    // Codebook for this row: wave-uniform address -> scalar loads (SGPR broadcast)
    const float* vr = values + (size_t)row * N_VALS;
    float v[N_VALS];
#pragma unroll
    for (int i = 0; i < N_VALS; ++i) v[i] = vr[i];

    const float4* xr   = (const float4*)(x   + (size_t)row * N_COLS);
    float4*       outr = (float4*)      (out + (size_t)row * N_COLS);

    // 2048 cols = 512 float4; 256 threads -> 2 iterations each, fully coalesced.
#pragma unroll
    for (int it = 0; it < 2; ++it) {
        const int j = threadIdx.x + it * 256;
        const float4 xv = xr[j];

        float xs[4] = {xv.x, xv.y, xv.z, xv.w};
        float os[4];
#pragma unroll
        for (int e = 0; e < 4; ++e) {
            const float xe = xs[e];
            float d0 = xe - v[0];
            d0 *= d0;
            float bd = d0;
            float bv = v[0];
#pragma unroll
            for (int i = 1; i < N_VALS; ++i) {
                float d = xe - v[i];
                d = d * d;
                const bool lt = (d < bd);   // strict <: first min wins ties
                bd = lt ? d : bd;
                bv = lt ? v[i] : bv;
            }
            os[e] = bv;
        }
        float4 o;
        o.x = os[0]; o.y = os[1]; o.z = os[2]; o.w = os[3];
        outr[j] = o;
    }
}

extern "C" void kernel_launch(void* const* d_in, const int* in_sizes, int n_in,
                              void* d_out, int out_size, void* d_ws, size_t ws_size,
                              hipStream_t stream) {
    const float* x      = (const float*)d_in[0];
    const float* values = (const float*)d_in[1];
    float* out          = (float*)d_out;

    vq_rowcodebook_kernel<<<N_ROWS, 256, 0, stream>>>(x, values, out);
}

// Round 2
// 86.785 us; speedup vs baseline: 1.0259x; 1.0259x over previous
//
#include <hip/hip_runtime.h>

// Per-row vector quantization:
//   x: [4096, 2048] fp32, values: [4096, 16] fp32
//   out[r][c] = values[r][argmin_v (x[r][c] - values[r][v])^2]
//
// Exact-semantics strategy (absmax must be 0):
//  - d_i = fl(fl(x - v_i)^2), same rounding as numpy (no fma contraction
//    possible in t*t; packed v_pk_add/mul_f32 are IEEE-identical per half).
//  - min via v_min3_f32 tree: finite non-NaN inputs -> md is bit-equal to
//    at least one d_i.
//  - descending equality-select (i = 15..0) leaves the LOWEST matching
//    index = numpy argmin first-occurrence tie-break.

#define N_ROWS 4096
#define N_COLS 2048
#define N_VALS 16

typedef float f32x2 __attribute__((ext_vector_type(2)));

static __device__ __forceinline__ float min3f(float a, float b, float c) {
    return fminf(fminf(a, b), c);   // folds to v_min3_f32
}

__global__ __launch_bounds__(256) void vq_rowcodebook_kernel(
    const float* __restrict__ x,
    const float* __restrict__ values,
    float* __restrict__ out)
{
    const int row = blockIdx.x;

    // Wave-uniform codebook address -> scalar loads (SGPR broadcast).
    const float* vr = values + (size_t)row * N_VALS;
    float v[N_VALS];
#pragma unroll
    for (int i = 0; i < N_VALS; ++i) v[i] = vr[i];

    const float4* xr   = (const float4*)(x   + (size_t)row * N_COLS);
    float4*       outr = (float4*)      (out + (size_t)row * N_COLS);

    // 2048 cols = 512 float4; 256 threads -> 2 iterations, fully coalesced.
#pragma unroll
    for (int it = 0; it < 2; ++it) {
        const int j = threadIdx.x + it * 256;
        const float4 xv = xr[j];

        float xs[4] = {xv.x, xv.y, xv.z, xv.w};
        float os[4];
#pragma unroll
        for (int e = 0; e < 4; ++e) {
            const float xe = xs[e];
            f32x2 xe2; xe2.x = xe; xe2.y = xe;

            // 16 distances as 8 packed float2 ops (v_pk_add/v_pk_mul).
            float d[N_VALS];
#pragma unroll
            for (int i = 0; i < N_VALS / 2; ++i) {
                f32x2 vv; vv.x = v[2 * i]; vv.y = v[2 * i + 1];
                f32x2 t  = xe2 - vv;
                f32x2 sq = t * t;
                d[2 * i]     = sq.x;
                d[2 * i + 1] = sq.y;
            }

            // min3 tree: depth 4, 8 instructions.
            const float t0 = min3f(d[0],  d[1],  d[2]);
            const float t1 = min3f(d[3],  d[4],  d[5]);
            const float t2 = min3f(d[6],  d[7],  d[8]);
            const float t3 = min3f(d[9],  d[10], d[11]);
            const float t4 = min3f(d[12], d[13], d[14]);
            const float u0 = min3f(t0, t1, t2);
            const float u1 = min3f(t3, t4, d[15]);
            const float md = fminf(u0, u1);

            // Descending overwrite: lowest matching index wins (first-min).
            float bv = 0.0f;
#pragma unroll
            for (int i = N_VALS - 1; i >= 0; --i)
                bv = (d[i] == md) ? v[i] : bv;

            os[e] = bv;
        }
        float4 o;
        o.x = os[0]; o.y = os[1]; o.z = os[2]; o.w = os[3];
        outr[j] = o;
    }
}

extern "C" void kernel_launch(void* const* d_in, const int* in_sizes, int n_in,
                              void* d_out, int out_size, void* d_ws, size_t ws_size,
                              hipStream_t stream) {
    const float* x      = (const float*)d_in[0];
    const float* values = (const float*)d_in[1];
    float* out          = (float*)d_out;

    vq_rowcodebook_kernel<<<N_ROWS, 256, 0, stream>>>(x, values, out);
}